// Round 16
// baseline (162.795 us; speedup 1.0000x reference)
//
#include <hip/hip_runtime.h>
#include <cstdint>
#include <cstddef>

// DigitCapsule dynamic routing, fp32.
// x[256,1152,8], W[1152,10,16,8], out v[256,10,16].
// Design: lane = q*16 + d. vsum trick: logits at round r = votes.(v0+..+v_{r-1}).
// R16 = R15 (W+x in LDS, DPP rowsum, attr(3,4) groove) with ONE change:
// CA 8->4. R11/R14/R15 all cluster at ~40-44us with no pipe saturated
// (VALU<=50%, LDS 43%, HBM 9%, Occ 20-26%) -> dependent-chain latency at
// ~2 effective waves/SIMD. The residency cap is LDS (49KB -> 3 blocks/CU).
// CA=4: LDS ~25KB -> 6 blocks/CU LDS-capable (VGPR/attr then cap at 4-5
// waves/SIMD), grid (288,8)=2304 blocks for finer tail granularity.
constexpr int Bn = 256, In = 1152, Pn = 8, Jn = 10, Dn = 16;
constexpr int CA = 4, NCH = In / CA;  // 288 chunks
constexpr int PADX = 9;               // x row pad: 8 used + 1 (bank spread)

template <int CTRL>
__device__ __forceinline__ float dpp_add(float v) {
  const int s =
      __builtin_amdgcn_update_dpp(0, __float_as_int(v), CTRL, 0xf, 0xf, true);
  return v + __int_as_float(s);  // fuses to v_add_f32_dpp
}

// Sum over the 16 lanes of each row (lane&15 = d); every lane gets the sum.
// quad_perm xor1=0xB1, xor2=0x4E, row_ror:4=0x124, row_ror:8=0x128.
// Pure VALU - nothing on the LDS pipe.
__device__ __forceinline__ float rowsum16(float v) {
  v = dpp_add<0xB1>(v);
  v = dpp_add<0x4E>(v);
  v = dpp_add<0x124>(v);
  v = dpp_add<0x128>(v);
  return v;
}

__device__ __forceinline__ float dot8(const float4 a0, const float4 a1,
                                      const float4 b0, const float4 b1) {
  float s = a0.x * b0.x;
  s = fmaf(a0.y, b0.y, s); s = fmaf(a0.z, b0.z, s); s = fmaf(a0.w, b0.w, s);
  s = fmaf(a1.x, b1.x, s); s = fmaf(a1.y, b1.y, s); s = fmaf(a1.z, b1.z, s);
  s = fmaf(a1.w, b1.w, s);
  return s;
}

// capsV: one routing round's weighted vote sum over an i-chunk, 2 b's/thread.
// thread: d = t&15, q = t>>4; b0 = blockIdx.y*32 + q, b1 = b0 + 16.
// block = (chunk, b-group of 32).
// LDS W (20KB): 16B units, unit = ((ii*Jn+j)*2+h)*16 + d (d-transposed:
//   lane d's b128 read -> 2-way bank alias, free; q-groups broadcast).
// LDS x (4.6KB): [32 b][PADX float4]; 4 distinct read addrs per wave land
//   on disjoint bank quads (stride 9 units = 36 dwords ≡ 4 mod 32).
// MODE 0: softmax of zero logits = 0.1 exactly -> raw vote sum * 0.1.
template <int MODE>
__global__ __launch_bounds__(256)
__attribute__((amdgpu_waves_per_eu(3, 4)))
void capsV(const float* __restrict__ x, const float* __restrict__ w,
           const float* __restrict__ vsumT, float* __restrict__ spart) {
  __shared__ float4 wlds[CA * Jn * 2 * 16];  // 1280 units = 20 KB
  __shared__ float4 xlds[32 * PADX];         // 4.6 KB
  const int t = threadIdx.x;
  const int d = t & 15, q = t >> 4;
  const int ch = blockIdx.x;
  const int bbase = blockIdx.y * 32;
  const int b0 = bbase + q, b1 = b0 + 16;
  const int i0 = ch * CA;

  // ---- stage W chunk: 1280 units / 256 threads = 5 each (coalesced) ----
  {
    const float4* wg =
        reinterpret_cast<const float4*>(w + (size_t)i0 * (Jn * Dn * Pn));
    for (int k = 0; k < 5; ++k) {
      const int g = t + k * 256;
      const int h = g & 1, dd = (g >> 1) & 15, ij = g >> 5;
      wlds[(ij * 2 + h) * 16 + dd] = wg[g];
    }
  }
  // ---- stage x chunk: 32 b's x 8 float4 = 256 units, one per thread ----
  {
    const int bl = t >> 3, idx = t & 7;
    xlds[bl * PADX + idx] = reinterpret_cast<const float4*>(
        x + ((size_t)(bbase + bl) * In + i0) * Pn)[idx];
  }

  float vs0[Jn], vs1[Jn], acc0[Jn], acc1[Jn];
  #pragma unroll
  for (int j = 0; j < Jn; ++j) {
    acc0[j] = 0.f; acc1[j] = 0.f;
    if (MODE) {
      vs0[j] = vsumT[((size_t)j * Bn + b0) * Dn + d];
      vs1[j] = vsumT[((size_t)j * Bn + b1) * Dn + d];
    }
  }

  __syncthreads();  // staged W and x visible to all waves

  for (int ii = 0; ii < CA; ++ii) {
    const float4 xa0 = xlds[q * PADX + ii * 2];
    const float4 xa1 = xlds[q * PADX + ii * 2 + 1];
    const float4 xb0 = xlds[(q + 16) * PADX + ii * 2];
    const float4 xb1 = xlds[(q + 16) * PADX + ii * 2 + 1];

    float vt0[Jn], vt1[Jn];
    #pragma unroll
    for (int j = 0; j < Jn; ++j) {
      const float4* wrow = &wlds[((ii * Jn + j) * 2) * 16 + d];
      const float4 w0 = wrow[0];   // h=0
      const float4 w1 = wrow[16];  // h=1
      vt0[j] = dot8(w0, w1, xa0, xa1);
      vt1[j] = dot8(w0, w1, xb0, xb1);
    }

    if (MODE) {
      float l0[Jn], l1[Jn];
      #pragma unroll
      for (int j = 0; j < Jn; ++j) {
        l0[j] = rowsum16(vt0[j] * vs0[j]);
        l1[j] = rowsum16(vt1[j] * vs1[j]);
      }
      // softmax over j; logits are O(0.1) so no max-subtraction needed.
      float sa = 0.f, sb = 0.f;
      #pragma unroll
      for (int j = 0; j < Jn; ++j) {
        l0[j] = __expf(l0[j]); sa += l0[j];
        l1[j] = __expf(l1[j]); sb += l1[j];
      }
      const float ia = __builtin_amdgcn_rcpf(sa);
      const float ib = __builtin_amdgcn_rcpf(sb);
      #pragma unroll
      for (int j = 0; j < Jn; ++j) {
        acc0[j] = fmaf(l0[j] * ia, vt0[j], acc0[j]);
        acc1[j] = fmaf(l1[j] * ib, vt1[j], acc1[j]);
      }
    } else {
      #pragma unroll
      for (int j = 0; j < Jn; ++j) { acc0[j] += vt0[j]; acc1[j] += vt1[j]; }
    }
  }

  const float cs = MODE ? 1.f : 0.1f;
  #pragma unroll
  for (int j = 0; j < Jn; ++j) {
    spart[(((size_t)ch * Jn + j) * Bn + b0) * Dn + d] = acc0[j] * cs;
    spart[(((size_t)ch * Jn + j) * Bn + b1) * Dn + d] = acc1[j] * cs;
  }
}

// capsF: reduce 288 chunk-partials, squash. 1024 threads: 8 chunk-groups
// (cg = t>>7) each privately sum 36 chunks for an 8b x 16d slab; LDS
// combine across cg; squash norm via DPP rowsum16 in the t<128 tail.
// block = (j, b-group of 8), grid (10, 32).
// MODE 0: vsumT = v ; MODE 1: vsumT += v ; MODE 2: out[b][j][d] = v.
template <int MODE>
__global__ __launch_bounds__(1024) void capsF(
    const float* __restrict__ spart, float* __restrict__ vsumT,
    float* __restrict__ out) {
  __shared__ float red[8][8][16];
  const int t = threadIdx.x;
  const int cg = t >> 7, r = t & 127, g = r >> 4, d = r & 15;
  const int j = blockIdx.x, b = blockIdx.y * 8 + g;

  const size_t cstride = (size_t)Jn * Bn * Dn;  // one chunk, in floats
  const size_t cstep = 8 * cstride;             // stride between my chunks
  const float* sp = spart + (((size_t)cg * Jn + j) * Bn + b) * Dn + d;
  float s0 = 0.f, s1 = 0.f;
  #pragma unroll 4
  for (int k = 0; k < NCH / 8; k += 2) {
    s0 += sp[0];
    s1 += sp[cstep];
    sp += 2 * cstep;
  }
  red[cg][g][d] = s0 + s1;
  __syncthreads();
  if (t < 128) {
    float z = 0.f;
    #pragma unroll
    for (int c = 0; c < 8; ++c) z += red[c][g][d];
    const float n2 = rowsum16(z * z);
    const float sc = n2 / (1.f + n2) / sqrtf(n2 + 1e-7f);
    const float v = z * sc;
    if (MODE == 2) {
      out[((size_t)b * Jn + j) * Dn + d] = v;
    } else if (MODE == 1) {
      vsumT[((size_t)j * Bn + b) * Dn + d] += v;
    } else {
      vsumT[((size_t)j * Bn + b) * Dn + d] = v;
    }
  }
}

extern "C" void kernel_launch(void* const* d_in, const int* in_sizes, int n_in,
                              void* d_out, int out_size, void* d_ws, size_t ws_size,
                              hipStream_t stream) {
  const float* x = (const float*)d_in[0];  // [256,1152,8]
  const float* w = (const float*)d_in[1];  // [1152,10,16,8]
  float* vsumT = (float*)d_ws;                      // [J][B][D]   0.16 MB
  float* spart = vsumT + (size_t)Jn * Bn * Dn;      // [NCH][J][B][D] 47.2 MB
  float* out = (float*)d_out;                       // [256,10,16]

  const dim3 gV(NCH, Bn / 32), gF(Jn, Bn / 8);

  capsV<0><<<gV, 256, 0, stream>>>(x, w, nullptr, spart);
  capsF<0><<<gF, 1024, 0, stream>>>(spart, vsumT, out);   // vsum = v0

  capsV<1><<<gV, 256, 0, stream>>>(x, w, vsumT, spart);   // round 1
  capsF<1><<<gF, 1024, 0, stream>>>(spart, vsumT, out);   // vsum += v1

  capsV<1><<<gV, 256, 0, stream>>>(x, w, vsumT, spart);   // round 2
  capsF<2><<<gF, 1024, 0, stream>>>(spart, vsumT, out);   // out = v2
}

// Round 17
// 158.299 us; speedup vs baseline: 1.0284x; 1.0284x over previous
//
#include <hip/hip_runtime.h>
#include <cstdint>
#include <cstddef>

// DigitCapsule dynamic routing, fp32.
// x[256,1152,8], W[1152,10,16,8], out v[256,10,16].
// Design: lane = q*16 + d. vsum trick: logits at round r = votes.(v0+..+v_{r-1}).
// R17 = R16 (W+x in LDS, zero-VMEM inner loop, DPP rowsum, attr(3,4),
// CA=4) with the inner arithmetic PACKED (v_pk_mul/fma_f32 via v2f):
//   dots: even/odd p-pairs, 160->100 slots; softmax mul/sum/acc packed
//   across the two b's; rowsum (DPP) and exp stay scalar.
// R9's packed attempt failed because the allocator re-sank GLOBAL loads;
// the inner loop now has zero global ops (R14), so that failure mode is
// structurally absent. VALU issue is ~50% of capsV's 40us and nothing
// occupancy-shaped has moved it (R7/R8/R16 all null) -> cut issue count.
constexpr int Bn = 256, In = 1152, Pn = 8, Jn = 10, Dn = 16;
constexpr int CA = 4, NCH = In / CA;  // 288 chunks
constexpr int PADX = 9;               // x row pad (bank spread)

typedef float v2f __attribute__((ext_vector_type(2)));

template <int CTRL>
__device__ __forceinline__ float dpp_add(float v) {
  const int s =
      __builtin_amdgcn_update_dpp(0, __float_as_int(v), CTRL, 0xf, 0xf, true);
  return v + __int_as_float(s);  // fuses to v_add_f32_dpp
}

// Sum over the 16 lanes of each row (lane&15 = d); every lane gets the sum.
// quad_perm xor1=0xB1, xor2=0x4E, row_ror:4=0x124, row_ror:8=0x128. Pure VALU.
__device__ __forceinline__ float rowsum16(float v) {
  v = dpp_add<0xB1>(v);
  v = dpp_add<0x4E>(v);
  v = dpp_add<0x124>(v);
  v = dpp_add<0x128>(v);
  return v;
}

// Packed dot over p: returns {sum of even p terms, sum of odd p terms}.
// 1 pk_mul + 3 pk_fma; caller adds the two halves (1 scalar add).
__device__ __forceinline__ v2f pkdot8(const float4 w0, const float4 w1,
                                      const float4 x0, const float4 x1) {
  v2f wa, wb, wc, wd, xa, xb, xc, xd;
  wa.x = w0.x; wa.y = w0.y; wb.x = w0.z; wb.y = w0.w;
  wc.x = w1.x; wc.y = w1.y; wd.x = w1.z; wd.y = w1.w;
  xa.x = x0.x; xa.y = x0.y; xb.x = x0.z; xb.y = x0.w;
  xc.x = x1.x; xc.y = x1.y; xd.x = x1.z; xd.y = x1.w;
  v2f acc = wa * xa;
  acc = __builtin_elementwise_fma(wb, xb, acc);
  acc = __builtin_elementwise_fma(wc, xc, acc);
  acc = __builtin_elementwise_fma(wd, xd, acc);
  return acc;
}

// capsV: one routing round's weighted vote sum over an i-chunk, 2 b's/thread.
// thread: d = t&15, q = t>>4; b0 = blockIdx.y*32 + q, b1 = b0 + 16.
// block = (chunk, b-group of 32).
// LDS W (20KB): 16B units, unit = ((ii*Jn+j)*2+h)*16 + d (d-transposed).
// LDS x (4.6KB): [32 b][PADX float4].
// Packed state: vt2/vs2/acc2/e2[j] = {b0, b1} in one v2f.
// MODE 0: softmax of zero logits = 0.1 exactly -> raw vote sum * 0.1.
template <int MODE>
__global__ __launch_bounds__(256)
__attribute__((amdgpu_waves_per_eu(3, 4)))
void capsV(const float* __restrict__ x, const float* __restrict__ w,
           const float* __restrict__ vsumT, float* __restrict__ spart) {
  __shared__ float4 wlds[CA * Jn * 2 * 16];  // 1280 units = 20 KB
  __shared__ float4 xlds[32 * PADX];         // 4.6 KB
  const int t = threadIdx.x;
  const int d = t & 15, q = t >> 4;
  const int ch = blockIdx.x;
  const int bbase = blockIdx.y * 32;
  const int b0 = bbase + q, b1 = b0 + 16;
  const int i0 = ch * CA;

  // ---- stage W chunk: 1280 units / 256 threads = 5 each (coalesced) ----
  {
    const float4* wg =
        reinterpret_cast<const float4*>(w + (size_t)i0 * (Jn * Dn * Pn));
    for (int k = 0; k < 5; ++k) {
      const int g = t + k * 256;
      const int h = g & 1, dd = (g >> 1) & 15, ij = g >> 5;
      wlds[(ij * 2 + h) * 16 + dd] = wg[g];
    }
  }
  // ---- stage x chunk: 32 b's x 8 float4 = 256 units, one per thread ----
  {
    const int bl = t >> 3, idx = t & 7;
    xlds[bl * PADX + idx] = reinterpret_cast<const float4*>(
        x + ((size_t)(bbase + bl) * In + i0) * Pn)[idx];
  }

  v2f vs2[Jn], acc2[Jn];
  #pragma unroll
  for (int j = 0; j < Jn; ++j) {
    acc2[j] = (v2f)(0.f);
    if (MODE) {
      vs2[j].x = vsumT[((size_t)j * Bn + b0) * Dn + d];
      vs2[j].y = vsumT[((size_t)j * Bn + b1) * Dn + d];
    }
  }

  __syncthreads();  // staged W and x visible to all waves

  for (int ii = 0; ii < CA; ++ii) {
    const float4 xa0 = xlds[q * PADX + ii * 2];
    const float4 xa1 = xlds[q * PADX + ii * 2 + 1];
    const float4 xb0 = xlds[(q + 16) * PADX + ii * 2];
    const float4 xb1 = xlds[(q + 16) * PADX + ii * 2 + 1];

    v2f vt2[Jn];
    #pragma unroll
    for (int j = 0; j < Jn; ++j) {
      const float4* wrow = &wlds[((ii * Jn + j) * 2) * 16 + d];
      const float4 w0 = wrow[0];   // h=0
      const float4 w1 = wrow[16];  // h=1
      const v2f pa = pkdot8(w0, w1, xa0, xa1);  // b0 even/odd halves
      const v2f pb = pkdot8(w0, w1, xb0, xb1);  // b1
      vt2[j].x = pa.x + pa.y;
      vt2[j].y = pb.x + pb.y;
    }

    if (MODE) {
      v2f e2[Jn], sum2 = (v2f)(0.f);
      #pragma unroll
      for (int j = 0; j < Jn; ++j) {
        const v2f lp = vt2[j] * vs2[j];  // pk_mul
        // logits O(0.1): no max-subtraction needed.
        e2[j].x = __expf(rowsum16(lp.x));
        e2[j].y = __expf(rowsum16(lp.y));
        sum2 += e2[j];  // pk_add
      }
      v2f inv2;
      inv2.x = __builtin_amdgcn_rcpf(sum2.x);
      inv2.y = __builtin_amdgcn_rcpf(sum2.y);
      #pragma unroll
      for (int j = 0; j < Jn; ++j)
        acc2[j] = __builtin_elementwise_fma(e2[j] * inv2, vt2[j], acc2[j]);
    } else {
      #pragma unroll
      for (int j = 0; j < Jn; ++j) acc2[j] += vt2[j];  // pk_add
    }
  }

  const float cs = MODE ? 1.f : 0.1f;
  #pragma unroll
  for (int j = 0; j < Jn; ++j) {
    spart[(((size_t)ch * Jn + j) * Bn + b0) * Dn + d] = acc2[j].x * cs;
    spart[(((size_t)ch * Jn + j) * Bn + b1) * Dn + d] = acc2[j].y * cs;
  }
}

// capsF: reduce 288 chunk-partials, squash. 1024 threads: 8 chunk-groups
// (cg = t>>7) each privately sum 36 chunks for an 8b x 16d slab; LDS
// combine across cg; squash norm via DPP rowsum16 in the t<128 tail.
// block = (j, b-group of 8), grid (10, 32).
// MODE 0: vsumT = v ; MODE 1: vsumT += v ; MODE 2: out[b][j][d] = v.
template <int MODE>
__global__ __launch_bounds__(1024) void capsF(
    const float* __restrict__ spart, float* __restrict__ vsumT,
    float* __restrict__ out) {
  __shared__ float red[8][8][16];
  const int t = threadIdx.x;
  const int cg = t >> 7, r = t & 127, g = r >> 4, d = r & 15;
  const int j = blockIdx.x, b = blockIdx.y * 8 + g;

  const size_t cstride = (size_t)Jn * Bn * Dn;  // one chunk, in floats
  const size_t cstep = 8 * cstride;             // stride between my chunks
  const float* sp = spart + (((size_t)cg * Jn + j) * Bn + b) * Dn + d;
  float s0 = 0.f, s1 = 0.f;
  #pragma unroll 4
  for (int k = 0; k < NCH / 8; k += 2) {
    s0 += sp[0];
    s1 += sp[cstep];
    sp += 2 * cstep;
  }
  red[cg][g][d] = s0 + s1;
  __syncthreads();
  if (t < 128) {
    float z = 0.f;
    #pragma unroll
    for (int c = 0; c < 8; ++c) z += red[c][g][d];
    const float n2 = rowsum16(z * z);
    const float sc = n2 / (1.f + n2) / sqrtf(n2 + 1e-7f);
    const float v = z * sc;
    if (MODE == 2) {
      out[((size_t)b * Jn + j) * Dn + d] = v;
    } else if (MODE == 1) {
      vsumT[((size_t)j * Bn + b) * Dn + d] += v;
    } else {
      vsumT[((size_t)j * Bn + b) * Dn + d] = v;
    }
  }
}

extern "C" void kernel_launch(void* const* d_in, const int* in_sizes, int n_in,
                              void* d_out, int out_size, void* d_ws, size_t ws_size,
                              hipStream_t stream) {
  const float* x = (const float*)d_in[0];  // [256,1152,8]
  const float* w = (const float*)d_in[1];  // [1152,10,16,8]
  float* vsumT = (float*)d_ws;                      // [J][B][D]   0.16 MB
  float* spart = vsumT + (size_t)Jn * Bn * Dn;      // [NCH][J][B][D] 47.2 MB
  float* out = (float*)d_out;                       // [256,10,16]

  const dim3 gV(NCH, Bn / 32), gF(Jn, Bn / 8);

  capsV<0><<<gV, 256, 0, stream>>>(x, w, nullptr, spart);
  capsF<0><<<gF, 1024, 0, stream>>>(spart, vsumT, out);   // vsum = v0

  capsV<1><<<gV, 256, 0, stream>>>(x, w, vsumT, spart);   // round 1
  capsF<1><<<gF, 1024, 0, stream>>>(spart, vsumT, out);   // vsum += v1

  capsV<1><<<gV, 256, 0, stream>>>(x, w, vsumT, spart);   // round 2
  capsF<2><<<gF, 1024, 0, stream>>>(spart, vsumT, out);   // out = v2
}